// Round 1
// baseline (3673.922 us; speedup 1.0000x reference)
//
#include <hip/hip_runtime.h>
#include <math.h>

// Problem constants
#define B 4
#define C 64
#define IMG_H 256
#define IMG_W 256
#define NN 65536   // IMG_H*IMG_W
#define HEADS 8
#define CHD 8      // C/HEADS

// Workspace layout (float offsets). Total ~134.3 MB.
// [0, 33554432): qk buffer [B][128][N]   (after k_dw_gram: reused as y[16M] + v[16M])
// [33554432, 33556992): gram [B*HEADS][80]  (64 q.k products, 8 q norms, 8 k norms)
// [33556992, 33573376): E [B][64][64]
#define OFF_QK   0
#define OFF_Y    0
#define OFF_V    16777216
#define OFF_GRAM 33554432
#define OFF_E    33556992

// ---------------------------------------------------------------------------
// K1: 1x1 conv x[B,64,N] -> qk[B,128,N]  (only q,k chunks of qkv; v chunk unused)
__global__ __launch_bounds__(256) void k_qk1x1(const float* __restrict__ x,
    const float* __restrict__ w, const float* __restrict__ bias,
    float* __restrict__ qk) {
  const int bx = blockIdx.x;
  const int b = bx >> 8;                       // 256 blocks per batch
  const int n = ((bx & 255) << 8) + threadIdx.x;
  const float* xb = x + ((size_t)b * C) * NN + n;
  float xv[C];
#pragma unroll
  for (int c = 0; c < C; ++c) xv[c] = xb[(size_t)c * NN];
  float* qb = qk + ((size_t)b * 128) * NN + n;
#pragma unroll 2
  for (int o = 0; o < 128; ++o) {
    float acc = bias[o];
#pragma unroll
    for (int c = 0; c < C; ++c) acc = fmaf(w[o * C + c], xv[c], acc);
    qb[(size_t)o * NN] = acc;
  }
}

// ---------------------------------------------------------------------------
__global__ void k_zero_gram(float* __restrict__ g) {
  int i = blockIdx.x * 256 + threadIdx.x;
  if (i < B * HEADS * 80) g[i] = 0.f;
}

// ---------------------------------------------------------------------------
// K2: depthwise 3x3 (+bias) fused with Gram/norm accumulation.
// q,k are never materialized: only sum_n q_c k_d, sum q_c^2, sum k_d^2 survive.
#define DG_CHUNKS 32
#define DG_ITERS 8   // 32 chunks * 256 thr * 8 iters = 65536 positions
__global__ __launch_bounds__(256) void k_dw_gram(const float* __restrict__ qk,
    const float* __restrict__ wdw, const float* __restrict__ bdw,
    float* __restrict__ gram) {
  const int bh = blockIdx.x / DG_CHUNKS;
  const int chunk = blockIdx.x % DG_CHUNKS;
  const int b = bh >> 3, h = bh & 7;
  const float* baseq = qk + ((size_t)b * 128 + h * CHD) * NN;
  const float* basek = qk + ((size_t)b * 128 + 64 + h * CHD) * NN;
  float acc[80];
#pragma unroll
  for (int i = 0; i < 80; ++i) acc[i] = 0.f;
  for (int it = 0; it < DG_ITERS; ++it) {
    const int n = chunk * (DG_ITERS * 256) + it * 256 + (int)threadIdx.x;
    const int py = n >> 8, px = n & 255;
    float qv[CHD], kv[CHD];
#pragma unroll
    for (int c = 0; c < CHD; ++c) {
      const int chq = h * CHD + c;
      const int chk = 64 + h * CHD + c;
      float aq = bdw[chq], ak = bdw[chk];
#pragma unroll
      for (int dy = -1; dy <= 1; ++dy) {
        const int yy = py + dy;
        if (yy < 0 || yy > IMG_H - 1) continue;
#pragma unroll
        for (int dx = -1; dx <= 1; ++dx) {
          const int xx = px + dx;
          if (xx < 0 || xx > IMG_W - 1) continue;
          const int nn2 = yy * IMG_W + xx;
          const int t = (dy + 1) * 3 + (dx + 1);
          aq = fmaf(wdw[chq * 9 + t], baseq[(size_t)c * NN + nn2], aq);
          ak = fmaf(wdw[chk * 9 + t], basek[(size_t)c * NN + nn2], ak);
        }
      }
      qv[c] = aq; kv[c] = ak;
    }
#pragma unroll
    for (int c = 0; c < CHD; ++c)
#pragma unroll
      for (int d = 0; d < CHD; ++d)
        acc[c * 8 + d] = fmaf(qv[c], kv[d], acc[c * 8 + d]);
#pragma unroll
    for (int c = 0; c < CHD; ++c) acc[64 + c] = fmaf(qv[c], qv[c], acc[64 + c]);
#pragma unroll
    for (int c = 0; c < CHD; ++c) acc[72 + c] = fmaf(kv[c], kv[c], acc[72 + c]);
  }
  const int lane = threadIdx.x & 63;
  float* gout = gram + bh * 80;
#pragma unroll 1
  for (int i = 0; i < 80; ++i) {
    float s = acc[i];
#pragma unroll
    for (int off = 32; off > 0; off >>= 1) s += __shfl_down(s, off, 64);
    if (lane == 0) atomicAdd(&gout[i], s);
  }
}

// ---------------------------------------------------------------------------
// K3: y = BN(conv1x1(x, w_m1))  (eval-mode BN folded to scale/shift)
__global__ __launch_bounds__(256) void k_m1_bn(const float* __restrict__ x,
    const float* __restrict__ w, const float* __restrict__ gamma,
    const float* __restrict__ beta, const float* __restrict__ mean,
    const float* __restrict__ var, float* __restrict__ y) {
  const int bx = blockIdx.x;
  const int b = bx >> 8;
  const int n = ((bx & 255) << 8) + threadIdx.x;
  const float* xb = x + ((size_t)b * C) * NN + n;
  float xv[C];
#pragma unroll
  for (int c = 0; c < C; ++c) xv[c] = xb[(size_t)c * NN];
  float* yb = y + ((size_t)b * C) * NN + n;
#pragma unroll 2
  for (int o = 0; o < C; ++o) {
    float acc = 0.f;
#pragma unroll
    for (int c = 0; c < C; ++c) acc = fmaf(w[o * C + c], xv[c], acc);
    const float sc = gamma[o] * rsqrtf(var[o] + 1e-5f);
    yb[(size_t)o * NN] = (acc - mean[o]) * sc + beta[o];
  }
}

// ---------------------------------------------------------------------------
// K4: x2 = sigmoid(conv5x5(y)); v = x * (1 + x2). 16x16 output tile per block,
// 64 out-channel accumulators per thread, input staged ICB channels at a time.
#define ICB 4
__global__ __launch_bounds__(256) void k_conv5_v(const float* __restrict__ y,
    const float* __restrict__ w2, const float* __restrict__ x,
    float* __restrict__ v) {
  const int bx = blockIdx.x;
  const int b = bx >> 8;
  const int tile = bx & 255;
  const int ty0 = (tile >> 4) * 16;
  const int tx0 = (tile & 15) * 16;
  const int tx = threadIdx.x & 15, ty = threadIdx.x >> 4;
  const float* yb = y + ((size_t)b * C) * NN;
  __shared__ float tile_s[ICB * 400];  // ICB channels of 20x20 halo tile
  float acc[C];
#pragma unroll
  for (int o = 0; o < C; ++o) acc[o] = 0.f;
  for (int c0 = 0; c0 < C; c0 += ICB) {
    __syncthreads();
    for (int i = threadIdx.x; i < ICB * 400; i += 256) {
      const int cc = i / 400, p = i % 400;
      const int r = p / 20, cl = p % 20;
      const int gy = ty0 - 2 + r, gx = tx0 - 2 + cl;
      float val = 0.f;
      if (gy >= 0 && gy < IMG_H && gx >= 0 && gx < IMG_W)
        val = yb[(size_t)(c0 + cc) * NN + gy * IMG_W + gx];
      tile_s[i] = val;
    }
    __syncthreads();
#pragma unroll
    for (int cc = 0; cc < ICB; ++cc) {
      float inv[25];
#pragma unroll
      for (int i = 0; i < 5; ++i)
#pragma unroll
        for (int j = 0; j < 5; ++j)
          inv[i * 5 + j] = tile_s[cc * 400 + (ty + i) * 20 + tx + j];
      const float* wc = w2 + (size_t)(c0 + cc) * 25;
#pragma unroll 2
      for (int o = 0; o < C; ++o) {
        const float* wo = wc + (size_t)o * (C * 25);
        float a = acc[o];
#pragma unroll
        for (int t = 0; t < 25; ++t) a = fmaf(wo[t], inv[t], a);
        acc[o] = a;
      }
    }
  }
  const int n = (ty0 + ty) * IMG_W + tx0 + tx;
  const float* xb = x + ((size_t)b * C) * NN + n;
  float* vb = v + ((size_t)b * C) * NN + n;
#pragma unroll 4
  for (int o = 0; o < C; ++o) {
    const float sg = 1.f / (1.f + __expf(-acc[o]));
    const float xval = xb[(size_t)o * NN];
    vb[(size_t)o * NN] = xval * (1.f + sg);
  }
}

// ---------------------------------------------------------------------------
// K6: softmax(attn) from gram+norms, then fold project_out weights:
// E[b][o][cv] = sum_{c'} wproj[o, h*8+c'] * attn[b,h,c',d]   (cv = h*8+d)
__global__ __launch_bounds__(256) void k_attn_e(const float* __restrict__ gram,
    const float* __restrict__ temp, const float* __restrict__ wproj,
    float* __restrict__ E) {
  __shared__ float attn[B * HEADS * CHD * CHD];  // 2048
  const int t = threadIdx.x;
  {
    const int b = t >> 6, h = (t >> 3) & 7, c = t & 7;
    const float* g = gram + (b * HEADS + h) * 80;
    const float qn = fmaxf(sqrtf(g[64 + c]), 1e-12f);
    const float tp = temp[h];
    float row[8];
    float mx = -1e30f;
#pragma unroll
    for (int d = 0; d < 8; ++d) {
      const float kn = fmaxf(sqrtf(g[72 + d]), 1e-12f);
      row[d] = g[c * 8 + d] / (qn * kn) * tp;
      mx = fmaxf(mx, row[d]);
    }
    float s = 0.f;
#pragma unroll
    for (int d = 0; d < 8; ++d) { row[d] = __expf(row[d] - mx); s += row[d]; }
    const float inv = 1.f / s;
#pragma unroll
    for (int d = 0; d < 8; ++d) attn[t * 8 + d] = row[d] * inv;
  }
  __syncthreads();
  for (int i = t; i < B * 64 * 64; i += 256) {
    const int b = i >> 12, o = (i >> 6) & 63, cv = i & 63;
    const int h = cv >> 3, d = cv & 7;
    float a = 0.f;
#pragma unroll
    for (int c2 = 0; c2 < 8; ++c2)
      a += wproj[o * C + h * 8 + c2] * attn[((b * HEADS + h) * 8 + c2) * 8 + d];
    E[i] = a;
  }
}

// ---------------------------------------------------------------------------
// K7: out[b,o,n] = bproj[o] + sum_cv E[b,o,cv] * v[b,cv,n]
// (fused attention-apply + project_out as one per-batch 64x64 1x1 conv)
__global__ __launch_bounds__(256) void k_out(const float* __restrict__ v,
    const float* __restrict__ E, const float* __restrict__ bproj,
    float* __restrict__ out) {
  const int bx = blockIdx.x;
  const int b = bx >> 8;
  const int n = ((bx & 255) << 8) + threadIdx.x;
  const float* vb = v + ((size_t)b * C) * NN + n;
  float vv[C];
#pragma unroll
  for (int c = 0; c < C; ++c) vv[c] = vb[(size_t)c * NN];
  const float* Eb = E + b * 4096;
  float* ob = out + ((size_t)b * C) * NN + n;
#pragma unroll 2
  for (int o = 0; o < C; ++o) {
    float acc = bproj[o];
#pragma unroll
    for (int c = 0; c < C; ++c) acc = fmaf(Eb[o * C + c], vv[c], acc);
    ob[(size_t)o * NN] = acc;
  }
}

// ---------------------------------------------------------------------------
extern "C" void kernel_launch(void* const* d_in, const int* in_sizes, int n_in,
                              void* d_out, int out_size, void* d_ws, size_t ws_size,
                              hipStream_t stream) {
  const float* x     = (const float*)d_in[0];
  const float* wqkv  = (const float*)d_in[1];
  const float* bqkv  = (const float*)d_in[2];
  const float* wdw   = (const float*)d_in[3];
  const float* bdw   = (const float*)d_in[4];
  const float* wproj = (const float*)d_in[5];
  const float* bproj = (const float*)d_in[6];
  const float* temp  = (const float*)d_in[7];
  const float* wm1   = (const float*)d_in[8];
  const float* gamma = (const float*)d_in[9];
  const float* beta  = (const float*)d_in[10];
  const float* mean  = (const float*)d_in[11];
  const float* var   = (const float*)d_in[12];
  const float* wm2   = (const float*)d_in[13];

  float* ws   = (float*)d_ws;
  float* qk   = ws + OFF_QK;
  float* ybuf = ws + OFF_Y;
  float* vbuf = ws + OFF_V;
  float* gram = ws + OFF_GRAM;
  float* Ebuf = ws + OFF_E;
  float* out  = (float*)d_out;

  k_qk1x1<<<dim3(B * 256), dim3(256), 0, stream>>>(x, wqkv, bqkv, qk);
  k_zero_gram<<<dim3(10), dim3(256), 0, stream>>>(gram);
  k_dw_gram<<<dim3(B * HEADS * DG_CHUNKS), dim3(256), 0, stream>>>(qk, wdw, bdw, gram);
  // y/v reuse the qk region; stream order guarantees k_dw_gram finished first
  k_m1_bn<<<dim3(B * 256), dim3(256), 0, stream>>>(x, wm1, gamma, beta, mean, var, ybuf);
  k_conv5_v<<<dim3(B * 256), dim3(256), 0, stream>>>(ybuf, wm2, x, vbuf);
  k_attn_e<<<dim3(1), dim3(256), 0, stream>>>(gram, temp, wproj, Ebuf);
  k_out<<<dim3(B * 256), dim3(256), 0, stream>>>(vbuf, Ebuf, bproj, out);
}

// Round 2
// 3655.635 us; speedup vs baseline: 1.0050x; 1.0050x over previous
//
#include <hip/hip_runtime.h>
#include <math.h>

// Problem constants
#define B 4
#define C 64
#define IMG_H 256
#define IMG_W 256
#define NN 65536   // IMG_H*IMG_W
#define HEADS 8
#define CHD 8      // C/HEADS

// Workspace layout (float offsets). Total ~134.3 MB.
// [0, 33554432): qk buffer [B][128][N]   (after k_dw_gram: reused as y[16M] + v[16M])
// [33554432, 33556992): gram [B*HEADS][80]  (64 q.k products, 8 q norms, 8 k norms)
// [33556992, 33573376): E [B][64][64]
#define OFF_QK   0
#define OFF_Y    0
#define OFF_V    16777216
#define OFF_GRAM 33554432
#define OFF_E    33556992

// ---------------------------------------------------------------------------
// K1: 1x1 conv x[B,64,N] -> qk[B,128,N]  (only q,k chunks of qkv; v chunk unused)
__global__ __launch_bounds__(256) void k_qk1x1(const float* __restrict__ x,
    const float* __restrict__ w, const float* __restrict__ bias,
    float* __restrict__ qk) {
  const int bx = blockIdx.x;
  const int b = bx >> 8;                       // 256 blocks per batch
  const int n = ((bx & 255) << 8) + threadIdx.x;
  const float* xb = x + ((size_t)b * C) * NN + n;
  float xv[C];
#pragma unroll
  for (int c = 0; c < C; ++c) xv[c] = xb[(size_t)c * NN];
  float* qb = qk + ((size_t)b * 128) * NN + n;
#pragma unroll 2
  for (int o = 0; o < 128; ++o) {
    float acc = bias[o];
#pragma unroll
    for (int c = 0; c < C; ++c) acc = fmaf(w[o * C + c], xv[c], acc);
    qb[(size_t)o * NN] = acc;
  }
}

// ---------------------------------------------------------------------------
__global__ void k_zero_gram(float* __restrict__ g) {
  int i = blockIdx.x * 256 + threadIdx.x;
  if (i < B * HEADS * 80) g[i] = 0.f;
}

// ---------------------------------------------------------------------------
// K2: depthwise 3x3 (+bias) fused with Gram/norm accumulation.
// q,k are never materialized: only sum_n q_c k_d, sum q_c^2, sum k_d^2 survive.
#define DG_CHUNKS 32
#define DG_ITERS 8   // 32 chunks * 256 thr * 8 iters = 65536 positions
__global__ __launch_bounds__(256) void k_dw_gram(const float* __restrict__ qk,
    const float* __restrict__ wdw, const float* __restrict__ bdw,
    float* __restrict__ gram) {
  const int bh = blockIdx.x / DG_CHUNKS;
  const int chunk = blockIdx.x % DG_CHUNKS;
  const int b = bh >> 3, h = bh & 7;
  const float* baseq = qk + ((size_t)b * 128 + h * CHD) * NN;
  const float* basek = qk + ((size_t)b * 128 + 64 + h * CHD) * NN;
  float acc[80];
#pragma unroll
  for (int i = 0; i < 80; ++i) acc[i] = 0.f;
  for (int it = 0; it < DG_ITERS; ++it) {
    const int n = chunk * (DG_ITERS * 256) + it * 256 + (int)threadIdx.x;
    const int py = n >> 8, px = n & 255;
    float qv[CHD], kv[CHD];
#pragma unroll
    for (int c = 0; c < CHD; ++c) {
      const int chq = h * CHD + c;
      const int chk = 64 + h * CHD + c;
      float aq = bdw[chq], ak = bdw[chk];
#pragma unroll
      for (int dy = -1; dy <= 1; ++dy) {
        const int yy = py + dy;
        if (yy < 0 || yy > IMG_H - 1) continue;
#pragma unroll
        for (int dx = -1; dx <= 1; ++dx) {
          const int xx = px + dx;
          if (xx < 0 || xx > IMG_W - 1) continue;
          const int nn2 = yy * IMG_W + xx;
          const int t = (dy + 1) * 3 + (dx + 1);
          aq = fmaf(wdw[chq * 9 + t], baseq[(size_t)c * NN + nn2], aq);
          ak = fmaf(wdw[chk * 9 + t], basek[(size_t)c * NN + nn2], ak);
        }
      }
      qv[c] = aq; kv[c] = ak;
    }
#pragma unroll
    for (int c = 0; c < CHD; ++c)
#pragma unroll
      for (int d = 0; d < CHD; ++d)
        acc[c * 8 + d] = fmaf(qv[c], kv[d], acc[c * 8 + d]);
#pragma unroll
    for (int c = 0; c < CHD; ++c) acc[64 + c] = fmaf(qv[c], qv[c], acc[64 + c]);
#pragma unroll
    for (int c = 0; c < CHD; ++c) acc[72 + c] = fmaf(kv[c], kv[c], acc[72 + c]);
  }
  const int lane = threadIdx.x & 63;
  float* gout = gram + bh * 80;
#pragma unroll 1
  for (int i = 0; i < 80; ++i) {
    float s = acc[i];
#pragma unroll
    for (int off = 32; off > 0; off >>= 1) s += __shfl_down(s, off, 64);
    if (lane == 0) atomicAdd(&gout[i], s);
  }
}

// ---------------------------------------------------------------------------
// K3: y = BN(conv1x1(x, w_m1))  (eval-mode BN folded to scale/shift)
__global__ __launch_bounds__(256) void k_m1_bn(const float* __restrict__ x,
    const float* __restrict__ w, const float* __restrict__ gamma,
    const float* __restrict__ beta, const float* __restrict__ mean,
    const float* __restrict__ var, float* __restrict__ y) {
  const int bx = blockIdx.x;
  const int b = bx >> 8;
  const int n = ((bx & 255) << 8) + threadIdx.x;
  const float* xb = x + ((size_t)b * C) * NN + n;
  float xv[C];
#pragma unroll
  for (int c = 0; c < C; ++c) xv[c] = xb[(size_t)c * NN];
  float* yb = y + ((size_t)b * C) * NN + n;
#pragma unroll 2
  for (int o = 0; o < C; ++o) {
    float acc = 0.f;
#pragma unroll
    for (int c = 0; c < C; ++c) acc = fmaf(w[o * C + c], xv[c], acc);
    const float sc = gamma[o] * rsqrtf(var[o] + 1e-5f);
    yb[(size_t)o * NN] = (acc - mean[o]) * sc + beta[o];
  }
}

// ---------------------------------------------------------------------------
// K4: x2 = sigmoid(conv5x5(y)); v = x * (1 + x2). 16x16 output tile per block,
// 64 out-channel accumulators per thread (ALL loops touching acc[]/inv[] are
// FULLY unrolled so both arrays stay in VGPRs — unroll-2 previously demoted
// acc[] to scratch: VGPR_Count=32, 4.3 GB scratch writes, 2479 us).
#define ICB 4
__global__ __launch_bounds__(256) void k_conv5_v(const float* __restrict__ y,
    const float* __restrict__ w2, const float* __restrict__ x,
    float* __restrict__ v) {
  const int bx = blockIdx.x;
  const int b = bx >> 8;
  const int tile = bx & 255;
  const int ty0 = (tile >> 4) * 16;
  const int tx0 = (tile & 15) * 16;
  const int tx = threadIdx.x & 15, ty = threadIdx.x >> 4;
  const float* yb = y + ((size_t)b * C) * NN;
  __shared__ float tile_s[ICB * 400];  // ICB channels of 20x20 halo tile
  float acc[C];
#pragma unroll
  for (int o = 0; o < C; ++o) acc[o] = 0.f;
  for (int c0 = 0; c0 < C; c0 += ICB) {
    __syncthreads();
    for (int i = threadIdx.x; i < ICB * 400; i += 256) {
      const int cc = i / 400, p = i % 400;
      const int r = p / 20, cl = p % 20;
      const int gy = ty0 - 2 + r, gx = tx0 - 2 + cl;
      float val = 0.f;
      if (gy >= 0 && gy < IMG_H && gx >= 0 && gx < IMG_W)
        val = yb[(size_t)(c0 + cc) * NN + gy * IMG_W + gx];
      tile_s[i] = val;
    }
    __syncthreads();
#pragma unroll 1
    for (int cc = 0; cc < ICB; ++cc) {
      float inv[25];
#pragma unroll
      for (int i = 0; i < 5; ++i)
#pragma unroll
        for (int j = 0; j < 5; ++j)
          inv[i * 5 + j] = tile_s[cc * 400 + (ty + i) * 20 + tx + j];
      const float* wc = w2 + (size_t)(c0 + cc) * 25;
#pragma unroll
      for (int o = 0; o < C; ++o) {
        const float* wo = wc + (size_t)o * (C * 25);
        float a = acc[o];
#pragma unroll
        for (int t = 0; t < 25; ++t) a = fmaf(wo[t], inv[t], a);
        acc[o] = a;
      }
    }
  }
  const int n = (ty0 + ty) * IMG_W + tx0 + tx;
  const float* xb = x + ((size_t)b * C) * NN + n;
  float* vb = v + ((size_t)b * C) * NN + n;
#pragma unroll
  for (int o = 0; o < C; ++o) {
    const float sg = 1.f / (1.f + __expf(-acc[o]));
    const float xval = xb[(size_t)o * NN];
    vb[(size_t)o * NN] = xval * (1.f + sg);
  }
}

// ---------------------------------------------------------------------------
// K6: softmax(attn) from gram+norms, then fold project_out weights:
// E[b][o][cv] = sum_{c'} wproj[o, h*8+c'] * attn[b,h,c',d]   (cv = h*8+d)
__global__ __launch_bounds__(256) void k_attn_e(const float* __restrict__ gram,
    const float* __restrict__ temp, const float* __restrict__ wproj,
    float* __restrict__ E) {
  __shared__ float attn[B * HEADS * CHD * CHD];  // 2048
  const int t = threadIdx.x;
  {
    const int b = t >> 6, h = (t >> 3) & 7, c = t & 7;
    const float* g = gram + (b * HEADS + h) * 80;
    const float qn = fmaxf(sqrtf(g[64 + c]), 1e-12f);
    const float tp = temp[h];
    float row[8];
    float mx = -1e30f;
#pragma unroll
    for (int d = 0; d < 8; ++d) {
      const float kn = fmaxf(sqrtf(g[72 + d]), 1e-12f);
      row[d] = g[c * 8 + d] / (qn * kn) * tp;
      mx = fmaxf(mx, row[d]);
    }
    float s = 0.f;
#pragma unroll
    for (int d = 0; d < 8; ++d) { row[d] = __expf(row[d] - mx); s += row[d]; }
    const float inv = 1.f / s;
#pragma unroll
    for (int d = 0; d < 8; ++d) attn[t * 8 + d] = row[d] * inv;
  }
  __syncthreads();
  for (int i = t; i < B * 64 * 64; i += 256) {
    const int b = i >> 12, o = (i >> 6) & 63, cv = i & 63;
    const int h = cv >> 3, d = cv & 7;
    float a = 0.f;
#pragma unroll
    for (int c2 = 0; c2 < 8; ++c2)
      a += wproj[o * C + h * 8 + c2] * attn[((b * HEADS + h) * 8 + c2) * 8 + d];
    E[i] = a;
  }
}

// ---------------------------------------------------------------------------
// K7: out[b,o,n] = bproj[o] + sum_cv E[b,o,cv] * v[b,cv,n]
// (fused attention-apply + project_out as one per-batch 64x64 1x1 conv)
__global__ __launch_bounds__(256) void k_out(const float* __restrict__ v,
    const float* __restrict__ E, const float* __restrict__ bproj,
    float* __restrict__ out) {
  const int bx = blockIdx.x;
  const int b = bx >> 8;
  const int n = ((bx & 255) << 8) + threadIdx.x;
  const float* vb = v + ((size_t)b * C) * NN + n;
  float vv[C];
#pragma unroll
  for (int c = 0; c < C; ++c) vv[c] = vb[(size_t)c * NN];
  const float* Eb = E + b * 4096;
  float* ob = out + ((size_t)b * C) * NN + n;
#pragma unroll 2
  for (int o = 0; o < C; ++o) {
    float acc = bproj[o];
#pragma unroll
    for (int c = 0; c < C; ++c) acc = fmaf(Eb[o * C + c], vv[c], acc);
    ob[(size_t)o * NN] = acc;
  }
}

// ---------------------------------------------------------------------------
extern "C" void kernel_launch(void* const* d_in, const int* in_sizes, int n_in,
                              void* d_out, int out_size, void* d_ws, size_t ws_size,
                              hipStream_t stream) {
  const float* x     = (const float*)d_in[0];
  const float* wqkv  = (const float*)d_in[1];
  const float* bqkv  = (const float*)d_in[2];
  const float* wdw   = (const float*)d_in[3];
  const float* bdw   = (const float*)d_in[4];
  const float* wproj = (const float*)d_in[5];
  const float* bproj = (const float*)d_in[6];
  const float* temp  = (const float*)d_in[7];
  const float* wm1   = (const float*)d_in[8];
  const float* gamma = (const float*)d_in[9];
  const float* beta  = (const float*)d_in[10];
  const float* mean  = (const float*)d_in[11];
  const float* var   = (const float*)d_in[12];
  const float* wm2   = (const float*)d_in[13];

  float* ws   = (float*)d_ws;
  float* qk   = ws + OFF_QK;
  float* ybuf = ws + OFF_Y;
  float* vbuf = ws + OFF_V;
  float* gram = ws + OFF_GRAM;
  float* Ebuf = ws + OFF_E;
  float* out  = (float*)d_out;

  k_qk1x1<<<dim3(B * 256), dim3(256), 0, stream>>>(x, wqkv, bqkv, qk);
  k_zero_gram<<<dim3(10), dim3(256), 0, stream>>>(gram);
  k_dw_gram<<<dim3(B * HEADS * DG_CHUNKS), dim3(256), 0, stream>>>(qk, wdw, bdw, gram);
  // y/v reuse the qk region; stream order guarantees k_dw_gram finished first
  k_m1_bn<<<dim3(B * 256), dim3(256), 0, stream>>>(x, wm1, gamma, beta, mean, var, ybuf);
  k_conv5_v<<<dim3(B * 256), dim3(256), 0, stream>>>(ybuf, wm2, x, vbuf);
  k_attn_e<<<dim3(1), dim3(256), 0, stream>>>(gram, temp, wproj, Ebuf);
  k_out<<<dim3(B * 256), dim3(256), 0, stream>>>(vbuf, Ebuf, bproj, out);
}